// Round 10
// baseline (335.007 us; speedup 1.0000x reference)
//
#include <hip/hip_runtime.h>
#include <hip/hip_fp8.h>
#include <stdint.h>
#include <math.h>

#define C_NUM 2048
#define N_TOT 4096
#define B_TOT 4096
#define KNOWN 1024

typedef __attribute__((ext_vector_type(16))) float f32x16;
typedef __attribute__((ext_vector_type(4))) int i32x4;
typedef __attribute__((ext_vector_type(8))) int i32x8;

__device__ __forceinline__ void gld16(const void* g, void* l) {
  __builtin_amdgcn_global_load_lds(
      (const __attribute__((address_space(1))) void*)g,
      (__attribute__((address_space(3))) void*)l, 16, 0, 0);
}

// ---- Kernel 1: transpose + fp8(e4m3) convert + colsum/norm2 partials -----
__global__ void transpose_stats_kernel(const float* __restrict__ prob,
                                       const float* __restrict__ prob_s,
                                       float* __restrict__ colsum,
                                       float* __restrict__ norm2,
                                       uint8_t* __restrict__ Pn) {
  __shared__ float tile[64][65];
  int tx = threadIdx.x;          // 0..63
  int ty = threadIdx.y;          // 0..3
  int c0 = blockIdx.x * 64;      // class tile (0..4095)
  int b0 = blockIdx.y * 64;      // batch tile
  const float* src = (c0 < C_NUM) ? prob : prob_s;
  int colbase = (c0 & (C_NUM - 1)) + tx;
  float s = 0.f, s2 = 0.f;
#pragma unroll
  for (int r = 0; r < 16; ++r) {
    int b = b0 + r * 4 + ty;
    float v = src[(size_t)b * C_NUM + colbase];
    tile[r * 4 + ty][tx] = v;
    s += v;
    s2 += v * v;
  }
  atomicAdd(&colsum[c0 + tx], s);
  atomicAdd(&norm2[c0 + tx], s2);
  __syncthreads();
#pragma unroll
  for (int r = 0; r < 16; ++r) {
    int i = c0 + r * 4 + ty;
    __hip_fp8_e4m3 q(tile[tx][r * 4 + ty]);
    Pn[(size_t)i * B_TOT + b0 + tx] = q.__x;
  }
}

// ---- Kernel 2: symmetric MX-fp8 GEMM (32x32x64) + softmax epilogue -------
// 128x128 tile, 512 threads = 8 waves (2x4 grid), wave tile 64x32 =
// acc[2] of mfma_scale_f32_32x32x64_f8f6f4 per k-instr (layout verified R9).
// A: LDS, BK=256B rows, double-buffered 2x32KB, staged via global_load_lds
// with 16-slot XOR swizzle  phys16B = logical ^ (row & 15)  (pre-permuted
// global source, linear LDS dest) -> 2 lanes/slot on fragment reads (free).
// B: DIRECT from global (32B/lane, same per-lane layout as A operand; L1
// absorbs the wr-pair reuse) -> zero LDS traffic for B.
// NT = 16 K-steps of 256B, 4 k-instr each. Triangular jobs, XCD-chunked.
__global__ __launch_bounds__(512) void simgemm_kernel(
    const uint8_t* __restrict__ Pn,
    const float* __restrict__ norm2,
    float* __restrict__ sumexp,
    float* __restrict__ pos) {
  __shared__ __align__(16) char lds[65536];  // A dbuf: buf q at q*32768

  const int tid = threadIdx.x;
  const int l = tid & 63;
  const int w = tid >> 6;            // wave 0..7
  const int wr = w >> 2, wc = w & 3; // 2x4 wave grid
  const int lr = l & 31;
  const int kh = l >> 5;             // k-half within instr

  // XCD-chunked bijective job swizzle: 528 = 8 * 66
  const int job = (blockIdx.x & 7) * 66 + (blockIdx.x >> 3);
  int t = job;
  int it = 0, rem = 32;
  while (t >= rem) { t -= rem; ++it; --rem; }
  const int jt = it + t;
  const int ib = it * 128;
  const int jb = jt * 128;

  // A staging: thread tid covers 16B granules G = tid + 512c (c=0..3) of the
  // 128x256B step-tile. row = G>>4, phys slot = G&15, logical = phys ^ (row&15)
  // ((G+512c)>>4 changes row by 32 -> same &15 -> same logical for all c).
  const int srow = tid >> 4;                       // 0..31
  const int glog = ((tid & 15) ^ (tid >> 4)) & 15;
  const char* gA = (const char*)Pn + (size_t)(ib + srow) * B_TOT + glog * 16;
  const int ldsOf = tid * 16;

  // B direct-global: lane holds Pn[jb + wc*32 + lr][k..k+32), k = step*256
  // + ki*64 + kh*32
  const char* gB = (const char*)Pn + (size_t)(jb + wc * 32 + lr) * B_TOT + kh * 32;

  f32x16 acc[2] = {{}, {}};

  // A fragment read: row = wr*64 + a*32 + lr; (row&15) == (l&15) for both a.
  const int ra0 = wr * 64 + lr;
  const int xorA = l & 15;

#define STAGE(buf, koff)                                  \
  do {                                                    \
    _Pragma("unroll")                                     \
    for (int c = 0; c < 4; ++c)                           \
      gld16(gA + (size_t)(32 * c) * B_TOT + (koff),       \
            lds + (buf) * 32768 + c * 8192 + ldsOf);      \
  } while (0)

  STAGE(0, 0);
  __syncthreads();

  int cur = 0;
  const int NT = B_TOT / 256;   // 16 K-steps
  for (int kt = 0; kt < NT; ++kt) {
    if (kt + 1 < NT) STAGE(cur ^ 1, (kt + 1) * 256);

    // B fragments for this step (4 k-instrs), straight from global/L1
    i32x8 bf[4];
#pragma unroll
    for (int ki = 0; ki < 4; ++ki) {
      const char* p = gB + kt * 256 + ki * 64;
      i32x4 lo = *(const i32x4*)p;
      i32x4 hi = *(const i32x4*)(p + 16);
      bf[ki] = __builtin_shufflevector(lo, hi, 0, 1, 2, 3, 4, 5, 6, 7);
    }

    const char* Abase = lds + cur * 32768;
    __builtin_amdgcn_s_setprio(1);
#pragma unroll
    for (int ki = 0; ki < 4; ++ki) {
      const int g = ki * 4 + kh * 2;
      const int p0 = (g ^ xorA) << 4;
      const int p1 = ((g + 1) ^ xorA) << 4;
#pragma unroll
      for (int a = 0; a < 2; ++a) {
        const char* p = Abase + (ra0 + a * 32) * 256;
        i32x4 lo = *(const i32x4*)(p + p0);
        i32x4 hi = *(const i32x4*)(p + p1);
        i32x8 af = __builtin_shufflevector(lo, hi, 0, 1, 2, 3, 4, 5, 6, 7);
        acc[a] = __builtin_amdgcn_mfma_scale_f32_32x32x64_f8f6f4(
            af, bf[ki], acc[a], 0, 0, 0, 0x7F7F7F7F, 0, 0x7F7F7F7F);
      }
    }
    __builtin_amdgcn_s_setprio(0);
    __syncthreads();
    cur ^= 1;
  }
#undef STAGE

  // ---- epilogue: v = 2*dot*inv_i*inv_j; uniform j>i rule, dual-row accum.
  // C/D layout (32x32, verified R9): col = lr, row = (reg&3)+8*(reg>>2)+4*kh
  const int jcol = jb + wc * 32 + lr;
  const float invj = 1.0f / fmaxf(sqrtf(norm2[jcol]), 1e-8f);
  float cs = 0.f;
#pragma unroll
  for (int a = 0; a < 2; ++a) {
#pragma unroll
    for (int reg = 0; reg < 16; ++reg) {
      const int i = ib + wr * 64 + a * 32 + (reg & 3) + 8 * (reg >> 2) + 4 * kh;
      const float invi = 1.0f / fmaxf(sqrtf(norm2[i]), 1e-8f);
      const float v = acc[a][reg] * 2.0f * invi * invj;
      float rs = 0.f;
      if (jcol > i) {
        if (jcol == (i ^ 2048)) {
          pos[i] = v;
          pos[jcol] = v;
        } else {
          float e = __expf(v);
          rs = (((i & 1024) == 0) && (jcol < KNOWN)) ? 1.0f : e;
          cs += (((jcol & 1024) == 0) && (i < KNOWN)) ? 1.0f : e;
        }
      }
      rs += __shfl_xor(rs, 1);
      rs += __shfl_xor(rs, 2);
      rs += __shfl_xor(rs, 4);
      rs += __shfl_xor(rs, 8);
      rs += __shfl_xor(rs, 16);
      if (lr == 0 && rs != 0.f) atomicAdd(&sumexp[i], rs);
    }
  }
  cs += __shfl_xor(cs, 32);
  if (l < 32 && cs != 0.f) atomicAdd(&sumexp[jb + wc * 32 + l], cs);
}

// ---- Kernel 3: finalize ---------------------------------------------------
__device__ float block_reduce_256(float v, volatile float* red) {
#pragma unroll
  for (int m = 32; m >= 1; m >>= 1) v += __shfl_xor(v, m);
  __syncthreads();
  if ((threadIdx.x & 63) == 0) red[threadIdx.x >> 6] = v;
  __syncthreads();
  return red[0] + red[1] + red[2] + red[3];
}

__global__ void finalize_kernel(const float* __restrict__ colsum,
                                const float* __restrict__ sumexp,
                                const float* __restrict__ pos,
                                float* __restrict__ out) {
  __shared__ float red[4];
  int t = threadIdx.x;
  float ce = 0.f, t1 = 0.f, t2 = 0.f;
  for (int i = t; i < N_TOT; i += 256) ce += logf(sumexp[i]) - pos[i];
  for (int c = t; c < C_NUM; c += 256) t1 += colsum[c];
  for (int c = t; c < C_NUM; c += 256) t2 += colsum[C_NUM + c];
  ce = block_reduce_256(ce, red);
  t1 = block_reduce_256(t1, red);
  t2 = block_reduce_256(t2, red);
  float e1 = 0.f, e2 = 0.f;
  for (int c = t; c < C_NUM; c += 256) {
    float m = colsum[c] / t1;
    e1 += m * logf(m);
  }
  for (int c = t; c < C_NUM; c += 256) {
    float m = colsum[C_NUM + c] / t2;
    e2 += m * logf(m);
  }
  e1 = block_reduce_256(e1, red);
  e2 = block_reduce_256(e2, red);
  if (t == 0) {
    float reg = logf((float)C_NUM) + e1 + logf((float)C_NUM) + e2;
    out[0] = ce / (float)N_TOT + reg;
  }
}

extern "C" void kernel_launch(void* const* d_in, const int* in_sizes, int n_in,
                              void* d_out, int out_size, void* d_ws, size_t ws_size,
                              hipStream_t stream) {
  const float* prob = (const float*)d_in[0];
  const float* prob_s = (const float*)d_in[1];
  float* out = (float*)d_out;

  char* ws = (char*)d_ws;
  uint8_t* Pn = (uint8_t*)ws;                                   // 16 MB fp8
  float* norm2 = (float*)(ws + (size_t)N_TOT * B_TOT);          // 4096 f32
  float* colsum = norm2 + N_TOT;                                // 4096 f32
  float* sumexp = colsum + N_TOT;                               // 4096 f32
  float* pos = sumexp + N_TOT;                                  // 4096 f32

  // zero the atomic accumulators (norm2, colsum, sumexp contiguous)
  hipMemsetAsync(norm2, 0, (size_t)3 * N_TOT * sizeof(float), stream);

  transpose_stats_kernel<<<dim3(64, 64), dim3(64, 4), 0, stream>>>(
      prob, prob_s, colsum, norm2, Pn);
  simgemm_kernel<<<528, 512, 0, stream>>>(Pn, norm2, sumexp, pos);
  finalize_kernel<<<1, 256, 0, stream>>>(colsum, sumexp, pos, out);
}

// Round 11
// 298.761 us; speedup vs baseline: 1.1213x; 1.1213x over previous
//
#include <hip/hip_runtime.h>
#include <hip/hip_fp8.h>
#include <stdint.h>
#include <math.h>

#define C_NUM 2048
#define N_TOT 4096
#define B_TOT 4096
#define KNOWN 1024

typedef __attribute__((ext_vector_type(16))) float f32x16;
typedef __attribute__((ext_vector_type(4))) int i32x4;
typedef __attribute__((ext_vector_type(8))) int i32x8;

__device__ __forceinline__ void gld16(const void* g, void* l) {
  __builtin_amdgcn_global_load_lds(
      (const __attribute__((address_space(1))) void*)g,
      (__attribute__((address_space(3))) void*)l, 16, 0, 0);
}

// ---- Kernel 1: transpose + fp8(e4m3) convert + colsum/norm2 partials -----
__global__ void transpose_stats_kernel(const float* __restrict__ prob,
                                       const float* __restrict__ prob_s,
                                       float* __restrict__ colsum,
                                       float* __restrict__ norm2,
                                       uint8_t* __restrict__ Pn) {
  __shared__ float tile[64][65];
  int tx = threadIdx.x;          // 0..63
  int ty = threadIdx.y;          // 0..3
  int c0 = blockIdx.x * 64;      // class tile (0..4095)
  int b0 = blockIdx.y * 64;      // batch tile
  const float* src = (c0 < C_NUM) ? prob : prob_s;
  int colbase = (c0 & (C_NUM - 1)) + tx;
  float s = 0.f, s2 = 0.f;
#pragma unroll
  for (int r = 0; r < 16; ++r) {
    int b = b0 + r * 4 + ty;
    float v = src[(size_t)b * C_NUM + colbase];
    tile[r * 4 + ty][tx] = v;
    s += v;
    s2 += v * v;
  }
  atomicAdd(&colsum[c0 + tx], s);
  atomicAdd(&norm2[c0 + tx], s2);
  __syncthreads();
#pragma unroll
  for (int r = 0; r < 16; ++r) {
    int i = c0 + r * 4 + ty;
    __hip_fp8_e4m3 q(tile[tx][r * 4 + ty]);
    Pn[(size_t)i * B_TOT + b0 + tx] = q.__x;
  }
}

// ---- Kernel 2: build B' — B operand pre-swizzled into fragment order ------
// B'[c][q][s][32B] = Pn[c*32 + (s&31)][q*64 + (s>>5)*32 .. +32)
// so a wave's B-fragment load is 64 lanes x 32B fully contiguous.
__global__ void bprime_kernel(const uint8_t* __restrict__ Pn,
                              uint8_t* __restrict__ Bp) {
  int T = blockIdx.x * 256 + threadIdx.x;       // 0 .. 512K-1
  int s = T & 63;
  int q = (T >> 6) & 63;
  int c = T >> 12;
  const i32x4* src = (const i32x4*)(Pn + (size_t)(c * 32 + (s & 31)) * B_TOT +
                                    q * 64 + (s >> 5) * 32);
  i32x4* dst = (i32x4*)(Bp + (size_t)T * 32);
  dst[0] = src[0];
  dst[1] = src[1];
}

// ---- Kernel 3: symmetric MX-fp8 GEMM (32x32x64) + softmax epilogue -------
// 128x128 tile, 512 threads = 8 waves (2x4 grid), wave tile 64x32 = acc[2].
// A: LDS, BK=256B rows, dbuf 2x32KB, staged via global_load_lds with the
// VERIFIED 16-slot XOR swizzle (phys16B = logical ^ (row&15), pre-permuted
// global source, linear LDS dest) -> 0 bank conflicts (R10-measured).
// B: direct from B' (coalesced 2KB/wave fragment loads, L2-resident).
// All operand/C-D layouts verified R9/R10. Triangular jobs, XCD-chunked.
__global__ __launch_bounds__(512) void simgemm_kernel(
    const uint8_t* __restrict__ Pn,
    const uint8_t* __restrict__ Bp,
    const float* __restrict__ norm2,
    float* __restrict__ sumexp,
    float* __restrict__ pos) {
  __shared__ __align__(16) char lds[65536];  // A dbuf: buf q at q*32768

  const int tid = threadIdx.x;
  const int l = tid & 63;
  const int w = tid >> 6;            // wave 0..7
  const int wr = w >> 2, wc = w & 3; // 2x4 wave grid
  const int lr = l & 31;
  const int kh = l >> 5;             // k-half within instr

  // XCD-chunked bijective job swizzle: 528 = 8 * 66
  const int job = (blockIdx.x & 7) * 66 + (blockIdx.x >> 3);
  int t = job;
  int it = 0, rem = 32;
  while (t >= rem) { t -= rem; ++it; --rem; }
  const int jt = it + t;
  const int ib = it * 128;
  const int jb = jt * 128;

  // A staging (R10-verified): thread tid covers 16B granules G = tid + 512c
  // (c=0..3); row = G>>4, phys slot = G&15, logical = phys ^ (row&15).
  const int srow = tid >> 4;                       // 0..31
  const int glog = ((tid & 15) ^ (tid >> 4)) & 15;
  const char* gA = (const char*)Pn + (size_t)(ib + srow) * B_TOT + glog * 16;
  const int ldsOf = tid * 16;

  // B' base for this wave: col-block c = (jb>>5)+wc ; +2048B per k-instr q
  const char* gBp = (const char*)Bp + ((size_t)((jb >> 5) + wc) << 17) + l * 32;

  f32x16 acc[2] = {{}, {}};

  // A fragment read: row = wr*64 + a*32 + lr; (row&15) == (l&15).
  const int ra0 = wr * 64 + lr;
  const int xorA = l & 15;

#define STAGE(buf, koff)                                  \
  do {                                                    \
    _Pragma("unroll")                                     \
    for (int c = 0; c < 4; ++c)                           \
      gld16(gA + (size_t)(32 * c) * B_TOT + (koff),       \
            lds + (buf) * 32768 + c * 8192 + ldsOf);      \
  } while (0)

  STAGE(0, 0);
  __syncthreads();

  int cur = 0;
  const int NT = B_TOT / 256;   // 16 K-steps
  for (int kt = 0; kt < NT; ++kt) {
    if (kt + 1 < NT) STAGE(cur ^ 1, (kt + 1) * 256);

    // B fragments for this step: 4 coalesced 32B loads per lane from B'
    i32x8 bf[4];
#pragma unroll
    for (int ki = 0; ki < 4; ++ki) {
      const char* p = gBp + (size_t)(kt * 4 + ki) * 2048;
      i32x4 lo = *(const i32x4*)p;
      i32x4 hi = *(const i32x4*)(p + 16);
      bf[ki] = __builtin_shufflevector(lo, hi, 0, 1, 2, 3, 4, 5, 6, 7);
    }

    const char* Abase = lds + cur * 32768;
    __builtin_amdgcn_s_setprio(1);
#pragma unroll
    for (int ki = 0; ki < 4; ++ki) {
      const int g = ki * 4 + kh * 2;
      const int p0 = (g ^ xorA) << 4;
      const int p1 = ((g + 1) ^ xorA) << 4;
#pragma unroll
      for (int a = 0; a < 2; ++a) {
        const char* p = Abase + (ra0 + a * 32) * 256;
        i32x4 lo = *(const i32x4*)(p + p0);
        i32x4 hi = *(const i32x4*)(p + p1);
        i32x8 af = __builtin_shufflevector(lo, hi, 0, 1, 2, 3, 4, 5, 6, 7);
        acc[a] = __builtin_amdgcn_mfma_scale_f32_32x32x64_f8f6f4(
            af, bf[ki], acc[a], 0, 0, 0, 0x7F7F7F7F, 0, 0x7F7F7F7F);
      }
    }
    __builtin_amdgcn_s_setprio(0);
    __syncthreads();
    cur ^= 1;
  }
#undef STAGE

  // ---- epilogue (R10-verified): v = 2*dot*inv_i*inv_j; uniform j>i rule.
  // C/D layout (32x32): col = lr, row = (reg&3)+8*(reg>>2)+4*kh
  const int jcol = jb + wc * 32 + lr;
  const float invj = 1.0f / fmaxf(sqrtf(norm2[jcol]), 1e-8f);
  float cs = 0.f;
#pragma unroll
  for (int a = 0; a < 2; ++a) {
#pragma unroll
    for (int reg = 0; reg < 16; ++reg) {
      const int i = ib + wr * 64 + a * 32 + (reg & 3) + 8 * (reg >> 2) + 4 * kh;
      const float invi = 1.0f / fmaxf(sqrtf(norm2[i]), 1e-8f);
      const float v = acc[a][reg] * 2.0f * invi * invj;
      float rs = 0.f;
      if (jcol > i) {
        if (jcol == (i ^ 2048)) {
          pos[i] = v;
          pos[jcol] = v;
        } else {
          float e = __expf(v);
          rs = (((i & 1024) == 0) && (jcol < KNOWN)) ? 1.0f : e;
          cs += (((jcol & 1024) == 0) && (i < KNOWN)) ? 1.0f : e;
        }
      }
      rs += __shfl_xor(rs, 1);
      rs += __shfl_xor(rs, 2);
      rs += __shfl_xor(rs, 4);
      rs += __shfl_xor(rs, 8);
      rs += __shfl_xor(rs, 16);
      if (lr == 0 && rs != 0.f) atomicAdd(&sumexp[i], rs);
    }
  }
  cs += __shfl_xor(cs, 32);
  if (l < 32 && cs != 0.f) atomicAdd(&sumexp[jb + wc * 32 + l], cs);
}

// ---- Kernel 4: finalize ---------------------------------------------------
__device__ float block_reduce_256(float v, volatile float* red) {
#pragma unroll
  for (int m = 32; m >= 1; m >>= 1) v += __shfl_xor(v, m);
  __syncthreads();
  if ((threadIdx.x & 63) == 0) red[threadIdx.x >> 6] = v;
  __syncthreads();
  return red[0] + red[1] + red[2] + red[3];
}

__global__ void finalize_kernel(const float* __restrict__ colsum,
                                const float* __restrict__ sumexp,
                                const float* __restrict__ pos,
                                float* __restrict__ out) {
  __shared__ float red[4];
  int t = threadIdx.x;
  float ce = 0.f, t1 = 0.f, t2 = 0.f;
  for (int i = t; i < N_TOT; i += 256) ce += logf(sumexp[i]) - pos[i];
  for (int c = t; c < C_NUM; c += 256) t1 += colsum[c];
  for (int c = t; c < C_NUM; c += 256) t2 += colsum[C_NUM + c];
  ce = block_reduce_256(ce, red);
  t1 = block_reduce_256(t1, red);
  t2 = block_reduce_256(t2, red);
  float e1 = 0.f, e2 = 0.f;
  for (int c = t; c < C_NUM; c += 256) {
    float m = colsum[c] / t1;
    e1 += m * logf(m);
  }
  for (int c = t; c < C_NUM; c += 256) {
    float m = colsum[C_NUM + c] / t2;
    e2 += m * logf(m);
  }
  e1 = block_reduce_256(e1, red);
  e2 = block_reduce_256(e2, red);
  if (t == 0) {
    float reg = logf((float)C_NUM) + e1 + logf((float)C_NUM) + e2;
    out[0] = ce / (float)N_TOT + reg;
  }
}

extern "C" void kernel_launch(void* const* d_in, const int* in_sizes, int n_in,
                              void* d_out, int out_size, void* d_ws, size_t ws_size,
                              hipStream_t stream) {
  const float* prob = (const float*)d_in[0];
  const float* prob_s = (const float*)d_in[1];
  float* out = (float*)d_out;

  char* ws = (char*)d_ws;
  uint8_t* Pn = (uint8_t*)ws;                                   // 16 MB fp8
  uint8_t* Bp = Pn + (size_t)N_TOT * B_TOT;                     // 16 MB fp8
  float* norm2 = (float*)(Bp + (size_t)N_TOT * B_TOT);          // 4096 f32
  float* colsum = norm2 + N_TOT;                                // 4096 f32
  float* sumexp = colsum + N_TOT;                               // 4096 f32
  float* pos = sumexp + N_TOT;                                  // 4096 f32

  // zero the atomic accumulators (norm2, colsum, sumexp contiguous)
  hipMemsetAsync(norm2, 0, (size_t)3 * N_TOT * sizeof(float), stream);

  transpose_stats_kernel<<<dim3(64, 64), dim3(64, 4), 0, stream>>>(
      prob, prob_s, colsum, norm2, Pn);
  bprime_kernel<<<2048, 256, 0, stream>>>(Pn, Bp);
  simgemm_kernel<<<528, 512, 0, stream>>>(Pn, Bp, norm2, sumexp, pos);
  finalize_kernel<<<1, 256, 0, stream>>>(colsum, sumexp, pos, out);
}

// Round 12
// 131.786 us; speedup vs baseline: 2.5421x; 2.2670x over previous
//
#include <hip/hip_runtime.h>
#include <hip/hip_fp8.h>
#include <stdint.h>
#include <math.h>

#define C_NUM 2048
#define N_TOT 4096
#define B_TOT 4096
#define KNOWN 1024

typedef __attribute__((ext_vector_type(4))) float f32x4;
typedef __attribute__((ext_vector_type(4))) int i32x4;
typedef __attribute__((ext_vector_type(8))) int i32x8;

__device__ __forceinline__ void gld16(const void* g, void* l) {
  __builtin_amdgcn_global_load_lds(
      (const __attribute__((address_space(1))) void*)g,
      (__attribute__((address_space(3))) void*)l, 16, 0, 0);
}

// ---- Kernel 1: transpose + fp8(e4m3) convert + colsum/norm2 partials -----
__global__ void transpose_stats_kernel(const float* __restrict__ prob,
                                       const float* __restrict__ prob_s,
                                       float* __restrict__ colsum,
                                       float* __restrict__ norm2,
                                       uint8_t* __restrict__ Pn) {
  __shared__ float tile[64][65];
  int tx = threadIdx.x;          // 0..63
  int ty = threadIdx.y;          // 0..3
  int c0 = blockIdx.x * 64;      // class tile (0..4095)
  int b0 = blockIdx.y * 64;      // batch tile
  const float* src = (c0 < C_NUM) ? prob : prob_s;
  int colbase = (c0 & (C_NUM - 1)) + tx;
  float s = 0.f, s2 = 0.f;
#pragma unroll
  for (int r = 0; r < 16; ++r) {
    int b = b0 + r * 4 + ty;
    float v = src[(size_t)b * C_NUM + colbase];
    tile[r * 4 + ty][tx] = v;
    s += v;
    s2 += v * v;
  }
  atomicAdd(&colsum[c0 + tx], s);
  atomicAdd(&norm2[c0 + tx], s2);
  __syncthreads();
#pragma unroll
  for (int r = 0; r < 16; ++r) {
    int i = c0 + r * 4 + ty;
    __hip_fp8_e4m3 q(tile[tx][r * 4 + ty]);
    Pn[(size_t)i * B_TOT + b0 + tx] = q.__x;
  }
}

// ---- Kernel 2: build B' — B operand in 16x16x128 fragment order ----------
// B'[c16][kt][l][32B] = Pn[c16*16 + (l&15)][kt*128 + (l>>4)*32 .. +32)
// -> a wave's B-fragment load is 64 lanes x 32B fully contiguous (2 KB).
__global__ void bprime_kernel(const uint8_t* __restrict__ Pn,
                              uint8_t* __restrict__ Bp) {
  int T = blockIdx.x * 256 + threadIdx.x;       // 0 .. 512K-1
  int l = T & 63;
  int kt = (T >> 6) & 31;
  int c16 = T >> 11;
  const i32x4* src = (const i32x4*)(Pn + (size_t)(c16 * 16 + (l & 15)) * B_TOT +
                                    kt * 128 + (l >> 4) * 32);
  i32x4* dst = (i32x4*)(Bp + (size_t)T * 32);
  dst[0] = src[0];
  dst[1] = src[1];
}

// ---- Kernel 3: symmetric MX-fp8 GEMM (16x16x128) + softmax epilogue ------
// R8 engine: triangular tile pairs (jt >= it), 128x128 tile, 512 threads =
// 8 waves (2x4); per-wave 64x32 output (acc[4][2] f32x4). BK=128 fp8 bytes,
// NT=32. A ONLY in LDS (16 KB/buffer, 32 KB dbuf) staged via global_load_lds
// with R8's 8-slot row-XOR swizzle (<=2-way banks on reads). B comes from
// B' as coalesced per-lane 32B fragment loads (L2/L3-resident).
__global__ __launch_bounds__(512) void simgemm_kernel(
    const uint8_t* __restrict__ Pn,
    const uint8_t* __restrict__ Bp,
    const float* __restrict__ norm2,
    float* __restrict__ sumexp,
    float* __restrict__ pos) {
  __shared__ __align__(16) char lds[32768];  // A dbuf: buf q at q*16384

  const int tid = threadIdx.x;
  const int l = tid & 63;
  const int w = tid >> 6;            // wave 0..7
  const int wr = w >> 2, wc = w & 3; // 2x4 wave grid

  // triangular decode: block t -> (it, jt) with jt >= it, 32x32 tile grid
  int t = blockIdx.x;
  int it = 0, rem = 32;
  while (t >= rem) { t -= rem; ++it; --rem; }
  const int jt = it + t;
  const int ib = it * 128;
  const int jb = jt * 128;
  const bool diag = (it == jt);

  // A staging (R8-verified): thread tid covers 16B granule G=tid of rows
  // 0..63 and G=tid+512 of rows 64..127. row = G>>3, phys gran = G&7,
  // logical = phys ^ (row&7) -> pre-permuted global column.
  const int srow = tid >> 3;                 // 0..63
  const int glog = (tid & 7) ^ (srow & 7);
  const char* gA = (const char*)Pn + (size_t)(ib + srow) * B_TOT + glog * 16;
  const int ldsOf = tid * 16;

  // B' base: col-16-block c16 = jb/16 + wc*2 (+fn); per (c16,kt): 2KB slab
  const char* gBp = (const char*)Bp + ((size_t)(jb >> 4) + wc * 2) * (32 * 2048) +
                    l * 32;

  f32x4 acc[4][2];
#pragma unroll
  for (int a = 0; a < 4; ++a)
#pragma unroll
    for (int b = 0; b < 2; ++b)
      acc[a][b] = (f32x4){0.f, 0.f, 0.f, 0.f};

  // A fragment read (R8-verified): rows of 128B, 32B per lane at swizzled
  // granules g = (l>>4)*2 ^ (l&7), partner g^1.
  const int arow = wr * 64 + (l & 15);
  const int ph0 = ((((l >> 4) * 2) ^ (l & 7)) * 16);

#define STAGE(buf, koff)                                           \
  do {                                                             \
    gld16(gA + (koff), lds + (buf) * 16384 + ldsOf);               \
    gld16(gA + (size_t)64 * B_TOT + (koff),                        \
          lds + (buf) * 16384 + 8192 + ldsOf);                     \
  } while (0)

  STAGE(0, 0);
  __syncthreads();

  int cur = 0;
  const int NT = B_TOT / 128;   // 32 K-steps (128 fp8 each)
  for (int kt = 0; kt < NT; ++kt) {
    if (kt + 1 < NT) STAGE(cur ^ 1, (kt + 1) * 128);

    // B fragments from B' (coalesced, L2-resident)
    i32x8 bf[2];
#pragma unroll
    for (int fn = 0; fn < 2; ++fn) {
      const char* p = gBp + (size_t)(fn * 32 + kt) * 2048;
      i32x4 lo = *(const i32x4*)p;
      i32x4 hi = *(const i32x4*)(p + 16);
      bf[fn] = __builtin_shufflevector(lo, hi, 0, 1, 2, 3, 4, 5, 6, 7);
    }

    const char* Abase = lds + cur * 16384;
    __builtin_amdgcn_s_setprio(1);
#pragma unroll
    for (int fm = 0; fm < 4; ++fm) {
      const char* p = Abase + (arow + fm * 16) * 128;
      i32x4 lo = *(const i32x4*)(p + ph0);
      i32x4 hi = *(const i32x4*)(p + (ph0 ^ 16));
      i32x8 af = __builtin_shufflevector(lo, hi, 0, 1, 2, 3, 4, 5, 6, 7);
#pragma unroll
      for (int fn = 0; fn < 2; ++fn)
        acc[fm][fn] = __builtin_amdgcn_mfma_scale_f32_16x16x128_f8f6f4(
            af, bf[fn], acc[fm][fn], 0, 0, 0, 0x7F7F7F7F, 0, 0x7F7F7F7F);
    }
    __builtin_amdgcn_s_setprio(0);
    __syncthreads();
    cur ^= 1;
  }
#undef STAGE

  // epilogue (R8-verified, norms inlined): v = 2 * dot * inv_i * inv_j
  float invj[2];
#pragma unroll
  for (int fn = 0; fn < 2; ++fn)
    invj[fn] = 1.0f / fmaxf(sqrtf(norm2[jb + wc * 32 + fn * 16 + (l & 15)]), 1e-8f);

  if (diag) {
#pragma unroll
    for (int fm = 0; fm < 4; ++fm) {
#pragma unroll
      for (int r = 0; r < 4; ++r) {
        const int i = ib + wr * 64 + fm * 16 + (l >> 4) * 4 + r;
        const float invi = 1.0f / fmaxf(sqrtf(norm2[i]), 1e-8f);
        float rs = 0.f;
#pragma unroll
        for (int fn = 0; fn < 2; ++fn) {
          const int j = jb + wc * 32 + fn * 16 + (l & 15);
          float v = acc[fm][fn][r] * 2.0f * invi * invj[fn];
          if (j != i)   // i^2048 can't occur inside a diagonal block
            rs += (((i & 1024) == 0) && (j < KNOWN)) ? 1.0f : __expf(v);
        }
        rs += __shfl_xor(rs, 1);
        rs += __shfl_xor(rs, 2);
        rs += __shfl_xor(rs, 4);
        rs += __shfl_xor(rs, 8);
        if ((l & 15) == 0) atomicAdd(&sumexp[i], rs);
      }
    }
  } else {
    float cs[2] = {0.f, 0.f};   // per-fn contribution to column rows j
#pragma unroll
    for (int fm = 0; fm < 4; ++fm) {
#pragma unroll
      for (int r = 0; r < 4; ++r) {
        const int i = ib + wr * 64 + fm * 16 + (l >> 4) * 4 + r;
        const float invi = 1.0f / fmaxf(sqrtf(norm2[i]), 1e-8f);
        float rs = 0.f;
#pragma unroll
        for (int fn = 0; fn < 2; ++fn) {
          const int j = jb + wc * 32 + fn * 16 + (l & 15);
          float v = acc[fm][fn][r] * 2.0f * invi * invj[fn];
          if (j == (i ^ 2048)) {
            pos[i] = v;          // symmetric entry has the same value
            pos[j] = v;
          } else {               // j != i always holds off-diagonal
            float e = __expf(v);
            rs += (((i & 1024) == 0) && (j < KNOWN)) ? 1.0f : e;
            cs[fn] += (((j & 1024) == 0) && (i < KNOWN)) ? 1.0f : e;
          }
        }
        rs += __shfl_xor(rs, 1);
        rs += __shfl_xor(rs, 2);
        rs += __shfl_xor(rs, 4);
        rs += __shfl_xor(rs, 8);
        if ((l & 15) == 0) atomicAdd(&sumexp[i], rs);
      }
    }
#pragma unroll
    for (int fn = 0; fn < 2; ++fn) {
      cs[fn] += __shfl_xor(cs[fn], 16);
      cs[fn] += __shfl_xor(cs[fn], 32);
    }
    if (l < 16) {
#pragma unroll
      for (int fn = 0; fn < 2; ++fn)
        atomicAdd(&sumexp[jb + wc * 32 + fn * 16 + l], cs[fn]);
    }
  }
}

// ---- Kernel 4: finalize ---------------------------------------------------
__device__ float block_reduce_256(float v, volatile float* red) {
#pragma unroll
  for (int m = 32; m >= 1; m >>= 1) v += __shfl_xor(v, m);
  __syncthreads();
  if ((threadIdx.x & 63) == 0) red[threadIdx.x >> 6] = v;
  __syncthreads();
  return red[0] + red[1] + red[2] + red[3];
}

__global__ void finalize_kernel(const float* __restrict__ colsum,
                                const float* __restrict__ sumexp,
                                const float* __restrict__ pos,
                                float* __restrict__ out) {
  __shared__ float red[4];
  int t = threadIdx.x;
  float ce = 0.f, t1 = 0.f, t2 = 0.f;
  for (int i = t; i < N_TOT; i += 256) ce += logf(sumexp[i]) - pos[i];
  for (int c = t; c < C_NUM; c += 256) t1 += colsum[c];
  for (int c = t; c < C_NUM; c += 256) t2 += colsum[C_NUM + c];
  ce = block_reduce_256(ce, red);
  t1 = block_reduce_256(t1, red);
  t2 = block_reduce_256(t2, red);
  float e1 = 0.f, e2 = 0.f;
  for (int c = t; c < C_NUM; c += 256) {
    float m = colsum[c] / t1;
    e1 += m * logf(m);
  }
  for (int c = t; c < C_NUM; c += 256) {
    float m = colsum[C_NUM + c] / t2;
    e2 += m * logf(m);
  }
  e1 = block_reduce_256(e1, red);
  e2 = block_reduce_256(e2, red);
  if (t == 0) {
    float reg = logf((float)C_NUM) + e1 + logf((float)C_NUM) + e2;
    out[0] = ce / (float)N_TOT + reg;
  }
}

extern "C" void kernel_launch(void* const* d_in, const int* in_sizes, int n_in,
                              void* d_out, int out_size, void* d_ws, size_t ws_size,
                              hipStream_t stream) {
  const float* prob = (const float*)d_in[0];
  const float* prob_s = (const float*)d_in[1];
  float* out = (float*)d_out;

  char* ws = (char*)d_ws;
  uint8_t* Pn = (uint8_t*)ws;                                   // 16 MB fp8
  uint8_t* Bp = Pn + (size_t)N_TOT * B_TOT;                     // 16 MB fp8
  float* norm2 = (float*)(Bp + (size_t)N_TOT * B_TOT);          // 4096 f32
  float* colsum = norm2 + N_TOT;                                // 4096 f32
  float* sumexp = colsum + N_TOT;                               // 4096 f32
  float* pos = sumexp + N_TOT;                                  // 4096 f32

  // zero the atomic accumulators (norm2, colsum, sumexp contiguous)
  hipMemsetAsync(norm2, 0, (size_t)3 * N_TOT * sizeof(float), stream);

  transpose_stats_kernel<<<dim3(64, 64), dim3(64, 4), 0, stream>>>(
      prob, prob_s, colsum, norm2, Pn);
  bprime_kernel<<<2048, 256, 0, stream>>>(Pn, Bp);
  simgemm_kernel<<<528, 512, 0, stream>>>(Pn, Bp, norm2, sumexp, pos);
  finalize_kernel<<<1, 256, 0, stream>>>(colsum, sumexp, pos, out);
}

// Round 13
// 114.752 us; speedup vs baseline: 2.9194x; 1.1484x over previous
//
#include <hip/hip_runtime.h>
#include <hip/hip_fp8.h>
#include <stdint.h>
#include <math.h>

#define C_NUM 2048
#define N_TOT 4096
#define B_TOT 4096
#define KNOWN 1024

typedef __attribute__((ext_vector_type(4))) float f32x4;
typedef __attribute__((ext_vector_type(4))) int i32x4;
typedef __attribute__((ext_vector_type(8))) int i32x8;

__device__ __forceinline__ void gld16(const void* g, void* l) {
  __builtin_amdgcn_global_load_lds(
      (const __attribute__((address_space(1))) void*)g,
      (__attribute__((address_space(3))) void*)l, 16, 0, 0);
}

// ---- Kernel 1: transpose + fp8 convert + colsum/norm2 (float4 loads) -----
// 256 threads/block, 64 class x 64 batch tile.
__global__ __launch_bounds__(256) void transpose_stats_kernel(
    const float* __restrict__ prob,
    const float* __restrict__ prob_s,
    float* __restrict__ colsum,
    float* __restrict__ norm2,
    uint8_t* __restrict__ Pn) {
  __shared__ float tile[64][68];
  const int tid = threadIdx.x;
  const int c0 = blockIdx.x * 64;      // class tile (0..4095)
  const int b0 = blockIdx.y * 64;      // batch tile
  const float* src = (c0 < C_NUM) ? prob : prob_s;
  const int colbase = (c0 & (C_NUM - 1));

  // phase 1: float4 loads, 4 per thread
  {
    const int row = tid >> 4;          // 0..15 (+16c)
    const int f4c = tid & 15;
#pragma unroll
    for (int c = 0; c < 4; ++c) {
      const float4 v = *(const float4*)(src + (size_t)(b0 + row + 16 * c) * C_NUM +
                                        colbase + f4c * 4);
      *(float4*)&tile[row + 16 * c][f4c * 4] = v;
    }
  }
  __syncthreads();

  // phase 2: per-class stats + fp8 pack (16 batch values / thread)
  {
    const int ci = tid >> 2;           // class within tile 0..63
    const int qb = tid & 3;            // batch quarter
    float s = 0.f, s2 = 0.f;
    uint8_t bytes[16];
#pragma unroll
    for (int k = 0; k < 16; ++k) {
      float v = tile[qb * 16 + k][ci];
      s += v;
      s2 += v * v;
      __hip_fp8_e4m3 q(v);
      bytes[k] = q.__x;
    }
    *(i32x4*)(Pn + (size_t)(c0 + ci) * B_TOT + b0 + qb * 16) = *(i32x4*)bytes;
    s += __shfl_xor(s, 1);
    s += __shfl_xor(s, 2);
    s2 += __shfl_xor(s2, 1);
    s2 += __shfl_xor(s2, 2);
    if (qb == 0) {
      atomicAdd(&colsum[c0 + ci], s);
      atomicAdd(&norm2[c0 + ci], s2);
    }
  }
}

// ---- Kernel 2: symmetric MX-fp8 GEMM (16x16x128) + softmax epilogue ------
// Triangular tile pairs (jt >= it), 128x128 tile, 256 threads = 4 waves
// (2x2); wave tile 64x64 (acc[4][4] f32x4) -> 1KB LDS read per MFMA.
// K-step = 256B (NT=16): A and B tiles 128 rows x 256B in ONE 64KB buffer.
// Layout (R10-MEASURED 0-conflict): 16B granule at logical slot g of row r
// stored at phys slot g ^ (r&15); staged via global_load_lds from the
// pre-permuted global column (linear LDS dest); reads XOR the same map.
__global__ __launch_bounds__(256) void simgemm_kernel(
    const uint8_t* __restrict__ Pn,
    const float* __restrict__ norm2,
    float* __restrict__ sumexp,
    float* __restrict__ pos) {
  __shared__ __align__(16) char lds[65536];  // A at 0, B at 32768

  const int tid = threadIdx.x;
  const int l = tid & 63;
  const int w = tid >> 6;            // wave 0..3
  const int wr = w >> 1, wc = w & 1; // 2x2 wave grid

  // triangular decode: block t -> (it, jt) with jt >= it, 32x32 tile grid
  int t = blockIdx.x;
  int it = 0, rem = 32;
  while (t >= rem) { t -= rem; ++it; --rem; }
  const int jt = it + t;
  const int ib = it * 128;
  const int jb = jt * 128;
  const bool diag = (it == jt);

  // staging: thread tid covers granules G = tid + 256c (c=0..7) of each
  // operand tile. row = G>>4 = (tid>>4) + 16c, phys slot = G&15 = tid&15,
  // logical slot = (tid&15) ^ ((tid>>4)&15)  (constant across c).
  const int glog = (tid & 15) ^ ((tid >> 4) & 15);
  const char* gA = (const char*)Pn + (size_t)(ib + (tid >> 4)) * B_TOT + glog * 16;
  const char* gB = (const char*)Pn + (size_t)(jb + (tid >> 4)) * B_TOT + glog * 16;
  const int ldsOf = tid * 16;

  f32x4 acc[4][4];
#pragma unroll
  for (int a = 0; a < 4; ++a)
#pragma unroll
    for (int b = 0; b < 4; ++b)
      acc[a][b] = (f32x4){0.f, 0.f, 0.f, 0.f};

  // fragment geometry: row = (wave)*64 + f*16 + (l&15); rows are 256B.
  // lane k-granules: lg = q*8 + (l>>4)*2, phys = lg ^ (l&15), partner ^1.
  const int lx = l & 15;
  const int ra = wr * 64 + lx;
  const int rb = wc * 64 + lx;

#define STAGE(koff)                                                        \
  do {                                                                     \
    _Pragma("unroll")                                                      \
    for (int c = 0; c < 8; ++c) {                                          \
      gld16(gA + (size_t)(16 * c) * B_TOT + (koff), lds + c * 4096 + ldsOf);\
      gld16(gB + (size_t)(16 * c) * B_TOT + (koff),                        \
            lds + 32768 + c * 4096 + ldsOf);                               \
    }                                                                      \
  } while (0)

  STAGE(0);
  __syncthreads();

  const int NT = B_TOT / 256;   // 16 K-steps of 256 bytes
  for (int kt = 0; kt < NT; ++kt) {
#pragma unroll
    for (int q = 0; q < 2; ++q) {
      const int ph0 = ((q * 8 + (l >> 4) * 2) ^ lx) * 16;
      i32x8 af[4];
#pragma unroll
      for (int fm = 0; fm < 4; ++fm) {
        const char* p = lds + (ra + fm * 16) * 256;
        i32x4 lo = *(const i32x4*)(p + ph0);
        i32x4 hi = *(const i32x4*)(p + (ph0 ^ 16));
        af[fm] = __builtin_shufflevector(lo, hi, 0, 1, 2, 3, 4, 5, 6, 7);
      }
      __builtin_amdgcn_s_setprio(1);
#pragma unroll
      for (int fn = 0; fn < 4; ++fn) {
        const char* p = lds + 32768 + (rb + fn * 16) * 256;
        i32x4 lo = *(const i32x4*)(p + ph0);
        i32x4 hi = *(const i32x4*)(p + (ph0 ^ 16));
        i32x8 bf = __builtin_shufflevector(lo, hi, 0, 1, 2, 3, 4, 5, 6, 7);
#pragma unroll
        for (int fm = 0; fm < 4; ++fm)
          acc[fm][fn] = __builtin_amdgcn_mfma_scale_f32_16x16x128_f8f6f4(
              af[fm], bf, acc[fm][fn], 0, 0, 0, 0x7F7F7F7F, 0, 0x7F7F7F7F);
      }
      __builtin_amdgcn_s_setprio(0);
    }
    __syncthreads();                 // all reads of this step done
    if (kt + 1 < NT) STAGE((kt + 1) * 256);
    __syncthreads();                 // staging landed (vmcnt drained)
  }
#undef STAGE

  // ---- epilogue: v = 2 * dot * inv_i * inv_j (norms inlined) ----
  float invj[4];
#pragma unroll
  for (int fn = 0; fn < 4; ++fn)
    invj[fn] = 1.0f / fmaxf(sqrtf(norm2[jb + wc * 64 + fn * 16 + lx]), 1e-8f);

  if (diag) {
#pragma unroll
    for (int fm = 0; fm < 4; ++fm) {
#pragma unroll
      for (int r = 0; r < 4; ++r) {
        const int i = ib + wr * 64 + fm * 16 + (l >> 4) * 4 + r;
        const float invi = 1.0f / fmaxf(sqrtf(norm2[i]), 1e-8f);
        float rs = 0.f;
#pragma unroll
        for (int fn = 0; fn < 4; ++fn) {
          const int j = jb + wc * 64 + fn * 16 + lx;
          float v = acc[fm][fn][r] * 2.0f * invi * invj[fn];
          if (j != i)   // i^2048 can't occur inside a diagonal block
            rs += (((i & 1024) == 0) && (j < KNOWN)) ? 1.0f : __expf(v);
        }
        rs += __shfl_xor(rs, 1);
        rs += __shfl_xor(rs, 2);
        rs += __shfl_xor(rs, 4);
        rs += __shfl_xor(rs, 8);
        if (lx == 0) atomicAdd(&sumexp[i], rs);
      }
    }
  } else {
    float cs[4] = {0.f, 0.f, 0.f, 0.f};
#pragma unroll
    for (int fm = 0; fm < 4; ++fm) {
#pragma unroll
      for (int r = 0; r < 4; ++r) {
        const int i = ib + wr * 64 + fm * 16 + (l >> 4) * 4 + r;
        const float invi = 1.0f / fmaxf(sqrtf(norm2[i]), 1e-8f);
        float rs = 0.f;
#pragma unroll
        for (int fn = 0; fn < 4; ++fn) {
          const int j = jb + wc * 64 + fn * 16 + lx;
          float v = acc[fm][fn][r] * 2.0f * invi * invj[fn];
          if (j == (i ^ 2048)) {
            pos[i] = v;          // symmetric entry, same value
            pos[j] = v;
          } else {               // j != i always holds off-diagonal
            float e = __expf(v);
            rs += (((i & 1024) == 0) && (j < KNOWN)) ? 1.0f : e;
            cs[fn] += (((j & 1024) == 0) && (i < KNOWN)) ? 1.0f : e;
          }
        }
        rs += __shfl_xor(rs, 1);
        rs += __shfl_xor(rs, 2);
        rs += __shfl_xor(rs, 4);
        rs += __shfl_xor(rs, 8);
        if (lx == 0) atomicAdd(&sumexp[i], rs);
      }
    }
#pragma unroll
    for (int fn = 0; fn < 4; ++fn) {
      cs[fn] += __shfl_xor(cs[fn], 16);
      cs[fn] += __shfl_xor(cs[fn], 32);
    }
    if (l < 16) {
#pragma unroll
      for (int fn = 0; fn < 4; ++fn)
        atomicAdd(&sumexp[jb + wc * 64 + fn * 16 + l], cs[fn]);
    }
  }
}

// ---- Kernel 3: finalize ---------------------------------------------------
__device__ float block_reduce_256(float v, volatile float* red) {
#pragma unroll
  for (int m = 32; m >= 1; m >>= 1) v += __shfl_xor(v, m);
  __syncthreads();
  if ((threadIdx.x & 63) == 0) red[threadIdx.x >> 6] = v;
  __syncthreads();
  return red[0] + red[1] + red[2] + red[3];
}

__global__ void finalize_kernel(const float* __restrict__ colsum,
                                const float* __restrict__ sumexp,
                                const float* __restrict__ pos,
                                float* __restrict__ out) {
  __shared__ float red[4];
  int t = threadIdx.x;
  float ce = 0.f, t1 = 0.f, t2 = 0.f;
  for (int i = t; i < N_TOT; i += 256) ce += logf(sumexp[i]) - pos[i];
  for (int c = t; c < C_NUM; c += 256) t1 += colsum[c];
  for (int c = t; c < C_NUM; c += 256) t2 += colsum[C_NUM + c];
  ce = block_reduce_256(ce, red);
  t1 = block_reduce_256(t1, red);
  t2 = block_reduce_256(t2, red);
  float e1 = 0.f, e2 = 0.f;
  for (int c = t; c < C_NUM; c += 256) {
    float m = colsum[c] / t1;
    e1 += m * logf(m);
  }
  for (int c = t; c < C_NUM; c += 256) {
    float m = colsum[C_NUM + c] / t2;
    e2 += m * logf(m);
  }
  e1 = block_reduce_256(e1, red);
  e2 = block_reduce_256(e2, red);
  if (t == 0) {
    float reg = logf((float)C_NUM) + e1 + logf((float)C_NUM) + e2;
    out[0] = ce / (float)N_TOT + reg;
  }
}

extern "C" void kernel_launch(void* const* d_in, const int* in_sizes, int n_in,
                              void* d_out, int out_size, void* d_ws, size_t ws_size,
                              hipStream_t stream) {
  const float* prob = (const float*)d_in[0];
  const float* prob_s = (const float*)d_in[1];
  float* out = (float*)d_out;

  char* ws = (char*)d_ws;
  uint8_t* Pn = (uint8_t*)ws;                                   // 16 MB fp8
  float* norm2 = (float*)(ws + (size_t)N_TOT * B_TOT);          // 4096 f32
  float* colsum = norm2 + N_TOT;                                // 4096 f32
  float* sumexp = colsum + N_TOT;                               // 4096 f32
  float* pos = sumexp + N_TOT;                                  // 4096 f32

  // zero the atomic accumulators (norm2, colsum, sumexp contiguous)
  hipMemsetAsync(norm2, 0, (size_t)3 * N_TOT * sizeof(float), stream);

  transpose_stats_kernel<<<dim3(64, 64), 256, 0, stream>>>(
      prob, prob_s, colsum, norm2, Pn);
  simgemm_kernel<<<528, 256, 0, stream>>>(Pn, norm2, sumexp, pos);
  finalize_kernel<<<1, 256, 0, stream>>>(colsum, sumexp, pos, out);
}